// Round 2
// baseline (1394.066 us; speedup 1.0000x reference)
//
#include <hip/hip_runtime.h>
#include <hip/hip_bf16.h>

#define LRES 8192
#define KNB 48
#define MAXREL 32
#define EFD 128
#define POS_DIM 16
#define RBF_BINS 16
#define NPAIR 25
#define FDIM (POS_DIM + NPAIR*RBF_BINS)   // 416

// workspace layout (float offsets)
#define WS_BB   0                          // 8192*15 = 122880
#define WS_CA4  (WS_BB + LRES*15)          // 8192*4  = 32768  -> 155648
#define WS_W1T  (WS_CA4 + LRES*4)          // 416*128 = 53248  -> 208896
#define WS_W2T  (WS_W1T + FDIM*EFD)        // 128*128 = 16384  -> 225280
#define WS_NBR  (WS_W2T + EFD*EFD)         // 393216 ints     -> end ~2.4MB

// ---------------------------------------------------------------- prep
__global__ __launch_bounds__(256) void prep_kernel(
    const float* __restrict__ coords, const float* __restrict__ noise,
    const float* __restrict__ w_e_w, const float* __restrict__ w_proj,
    float* __restrict__ ws)
{
    int t = blockIdx.x * blockDim.x + threadIdx.x;
    if (t < LRES) {
        float X[12];
        #pragma unroll
        for (int q = 0; q < 12; ++q) X[q] = coords[t*12+q] + 0.1f * noise[t*12+q];
        float Nx=X[0],Ny=X[1],Nz=X[2];
        float Ax=X[3],Ay=X[4],Az=X[5];
        float Cx=X[6],Cy=X[7],Cz=X[8];
        float Ox=X[9],Oy=X[10],Oz=X[11];
        float bx=Ax-Nx, by=Ay-Ny, bz=Az-Nz;
        float cx=Cx-Ax, cy=Cy-Ay, cz=Cz-Az;
        float ax = by*cz - bz*cy;
        float ay = bz*cx - bx*cz;
        float az = bx*cy - by*cx;
        float Bx = -0.58273431f*ax + 0.56802827f*bx - 0.54067466f*cx + Ax;
        float By = -0.58273431f*ay + 0.56802827f*by - 0.54067466f*cy + Ay;
        float Bz = -0.58273431f*az + 0.56802827f*bz - 0.54067466f*cz + Az;
        float* bb = ws + WS_BB + t*15;
        bb[0]=Nx; bb[1]=Ny; bb[2]=Nz;
        bb[3]=Ax; bb[4]=Ay; bb[5]=Az;
        bb[6]=Cx; bb[7]=Cy; bb[8]=Cz;
        bb[9]=Ox; bb[10]=Oy; bb[11]=Oz;
        bb[12]=Bx; bb[13]=By; bb[14]=Bz;
        float* ca = ws + WS_CA4 + t*4;
        ca[0]=Ax; ca[1]=Ay; ca[2]=Az; ca[3]=0.f;
    } else if (t < LRES + FDIM*EFD) {
        int idx = t - LRES;                // idx = f*128 + o
        int f = idx >> 7, o = idx & 127;
        ws[WS_W1T + idx] = w_e_w[o*FDIM + f];
    } else if (t < LRES + FDIM*EFD + EFD*EFD) {
        int idx = t - LRES - FDIM*EFD;
        int c = idx >> 7, o = idx & 127;
        ws[WS_W2T + idx] = w_proj[o*EFD + c];
    }
}

// ---------------------------------------------------------------- top-K
// One block per row. Distances kept in registers (32/thread); binary-search
// the 48th-smallest float-bit value, collect (bits<<32)|index keys, bitonic
// sort 256 -> exact jax.lax.top_k tie-break (lower index first).
__global__ __launch_bounds__(256) void topk_kernel(
    const float* __restrict__ ws, const float* __restrict__ mask,
    float* __restrict__ nbr_f, int* __restrict__ nbr_i)
{
    const int row = blockIdx.x;
    const int tid = threadIdx.x;
    __shared__ int s_red[4];
    __shared__ int s_cnt;
    __shared__ unsigned long long s_list[256];

    const float4* ca4 = (const float4*)(ws + WS_CA4);
    float4 ci = ca4[row];
    bool mi = (mask[row] != 0.0f);

    unsigned int v[32];
    #pragma unroll
    for (int q = 0; q < 32; ++q) {
        int j = tid + q*256;
        float4 cj = ca4[j];
        float dx = cj.x - ci.x, dy = cj.y - ci.y, dz = cj.z - ci.z;
        float d = sqrtf(dx*dx + dy*dy + dz*dz + 1e-6f);
        bool valid = mi && (mask[j] != 0.0f);
        v[q] = valid ? __float_as_uint(d) : 0x7F800000u;
    }

    unsigned int lo = 0, hi = 0x7F800000u;
    while (lo < hi) {
        unsigned int mid = lo + ((hi - lo) >> 1);
        int c = 0;
        #pragma unroll
        for (int q = 0; q < 32; ++q) c += (v[q] <= mid) ? 1 : 0;
        #pragma unroll
        for (int s = 1; s < 64; s <<= 1) c += __shfl_xor(c, s);
        if ((tid & 63) == 0) s_red[tid >> 6] = c;
        __syncthreads();
        c = s_red[0] + s_red[1] + s_red[2] + s_red[3];
        __syncthreads();
        if (c >= KNB) hi = mid; else lo = mid + 1;
    }

    if (tid == 0) s_cnt = 0;
    __syncthreads();
    #pragma unroll
    for (int q = 0; q < 32; ++q) {
        if (v[q] <= lo) {
            int pos = atomicAdd(&s_cnt, 1);
            if (pos < 256)
                s_list[pos] = ((unsigned long long)v[q] << 32) | (unsigned int)(tid + q*256);
        }
    }
    __syncthreads();
    int cnt = s_cnt; if (cnt > 256) cnt = 256;
    if (tid >= cnt) s_list[tid] = 0xFFFFFFFFFFFFFFFFull;
    __syncthreads();

    for (int k = 2; k <= 256; k <<= 1) {
        for (int s = k >> 1; s > 0; s >>= 1) {
            int ixj = tid ^ s;
            if (ixj > tid) {
                unsigned long long a = s_list[tid], b = s_list[ixj];
                bool up = ((tid & k) == 0);
                if ((a > b) == up) { s_list[tid] = b; s_list[ixj] = a; }
            }
            __syncthreads();
        }
    }

    if (tid < KNB) {
        unsigned int j = (unsigned int)(s_list[tid] & 0xFFFFFFFFu);
        nbr_f[row*KNB + tid] = (float)j;
        nbr_i[row*KNB + tid] = (int)j;
    }
}

// ---------------------------------------------------------------- edges
// 32 edges per 256-thread block: features -> LDS [416][32], GEMM1 (o=tid&127,
// h=tid>>7, 16 edges/thread), LayerNorm (shfl-reduce across o), GEMM2.
__global__ __launch_bounds__(256) void edge_kernel(
    const float* __restrict__ ws, const int* __restrict__ nbr_i,
    const int* __restrict__ res_idx, const int* __restrict__ chain_idx,
    const float* __restrict__ w_pos_w, const float* __restrict__ w_pos_b,
    const float* __restrict__ nsc, const float* __restrict__ nbi,
    const float* __restrict__ proj_b, float* __restrict__ out)
{
    __shared__ float feat[FDIM][32];     // 53248 B
    __shared__ float part[4][16];
    __shared__ int sI[32], sJ[32];

    const int tid = threadIdx.x;
    const int e0 = blockIdx.x * 32;

    if (tid < 32) {
        int gid = e0 + tid;
        sI[tid] = gid / KNB;
        sJ[tid] = nbr_i[gid];
    }
    __syncthreads();

    const float* bb = ws + WS_BB;
    // RBF features: 800 tasks = 25 pairs x 32 edges; e = p&31 -> conflict-free LDS
    for (int p = tid; p < 800; p += 256) {
        int e = p & 31;
        int pp = p >> 5;                  // 0..24
        int a = pp / 5, b = pp - 5*a;
        int i = sI[e], j = sJ[e];
        float dx = bb[i*15 + a*3 + 0] - bb[j*15 + b*3 + 0];
        float dy = bb[i*15 + a*3 + 1] - bb[j*15 + b*3 + 1];
        float dz = bb[i*15 + a*3 + 2] - bb[j*15 + b*3 + 2];
        float d = sqrtf(dx*dx + dy*dy + dz*dz + 1e-6f);
        int base = POS_DIM + pp*RBF_BINS;
        #pragma unroll
        for (int bin = 0; bin < RBF_BINS; ++bin) {
            float mu = 2.0f + (float)bin * (20.0f/15.0f);
            float t = (d - mu) * 0.8f;    // /sigma, sigma = 1.25
            feat[base + bin][e] = __expf(-t*t);
        }
    }
    // positional features: 512 tasks = 16 dims x 32 edges
    for (int q = tid; q < 512; q += 256) {
        int e = q & 31;
        int dd = q >> 5;
        int i = sI[e], j = sJ[e];
        int off = res_idx[i] - res_idx[j];
        int offc = off + MAXREL;
        offc = offc < 0 ? 0 : (offc > 2*MAXREL ? 2*MAXREL : offc);
        int enc = (chain_idx[i] == chain_idx[j]) ? offc : (2*MAXREL + 1);
        feat[dd][e] = w_pos_w[dd*(2*MAXREL+2) + enc] + w_pos_b[dd];
    }
    __syncthreads();

    const int o = tid & 127;
    const int h = tid >> 7;

    // GEMM1: ef1[e][o] = sum_f feat[f][e] * W1T[f][o]
    // feat reads are wave-broadcast (same addr across lanes) -> conflict-free.
    const float* W1T = ws + WS_W1T;
    float acc[16];
    #pragma unroll
    for (int m = 0; m < 16; ++m) acc[m] = 0.f;
    #pragma unroll 2
    for (int f = 0; f < FDIM; ++f) {
        float w = W1T[f*EFD + o];
        const float4* fr = (const float4*)(&feat[f][h*16]);
        float4 a0 = fr[0], a1 = fr[1], a2 = fr[2], a3 = fr[3];
        acc[0]  = fmaf(w, a0.x, acc[0]);  acc[1]  = fmaf(w, a0.y, acc[1]);
        acc[2]  = fmaf(w, a0.z, acc[2]);  acc[3]  = fmaf(w, a0.w, acc[3]);
        acc[4]  = fmaf(w, a1.x, acc[4]);  acc[5]  = fmaf(w, a1.y, acc[5]);
        acc[6]  = fmaf(w, a1.z, acc[6]);  acc[7]  = fmaf(w, a1.w, acc[7]);
        acc[8]  = fmaf(w, a2.x, acc[8]);  acc[9]  = fmaf(w, a2.y, acc[9]);
        acc[10] = fmaf(w, a2.z, acc[10]); acc[11] = fmaf(w, a2.w, acc[11]);
        acc[12] = fmaf(w, a3.x, acc[12]); acc[13] = fmaf(w, a3.y, acc[13]);
        acc[14] = fmaf(w, a3.z, acc[14]); acc[15] = fmaf(w, a3.w, acc[15]);
    }

    // LayerNorm over o (128 threads = 2 waves per h-group)
    float mean[16];
    #pragma unroll
    for (int m = 0; m < 16; ++m) {
        float s = acc[m];
        #pragma unroll
        for (int d = 1; d < 64; d <<= 1) s += __shfl_xor(s, d);
        if ((tid & 63) == 0) part[tid >> 6][m] = s;
    }
    __syncthreads();
    #pragma unroll
    for (int m = 0; m < 16; ++m)
        mean[m] = (part[2*h][m] + part[2*h+1][m]) * (1.0f/128.0f);
    __syncthreads();
    #pragma unroll
    for (int m = 0; m < 16; ++m) {
        float dv = acc[m] - mean[m];
        float s = dv * dv;
        #pragma unroll
        for (int d = 1; d < 64; d <<= 1) s += __shfl_xor(s, d);
        if ((tid & 63) == 0) part[tid >> 6][m] = s;
    }
    __syncthreads();
    float scl = nsc[o], bia = nbi[o];
    #pragma unroll
    for (int m = 0; m < 16; ++m) {
        float var = (part[2*h][m] + part[2*h+1][m]) * (1.0f/128.0f);
        float rstd = rsqrtf(var + 1e-5f);
        acc[m] = (acc[m] - mean[m]) * rstd * scl + bia;
    }
    __syncthreads();   // all feat (GEMM1) + part reads done before reuse

    // stash normalized values: feat[c][e] for c=o (16-way write conflict,
    // once per block -- negligible; padding would misalign float4)
    {
        float4* dst = (float4*)(&feat[o][h*16]);
        dst[0] = make_float4(acc[0],  acc[1],  acc[2],  acc[3]);
        dst[1] = make_float4(acc[4],  acc[5],  acc[6],  acc[7]);
        dst[2] = make_float4(acc[8],  acc[9],  acc[10], acc[11]);
        dst[3] = make_float4(acc[12], acc[13], acc[14], acc[15]);
    }
    __syncthreads();

    // GEMM2: ef2[e][o] = sum_c efn[c][e] * W2T[c][o] + b[o]
    const float* W2T = ws + WS_W2T;
    float acc2[16];
    #pragma unroll
    for (int m = 0; m < 16; ++m) acc2[m] = 0.f;
    #pragma unroll 2
    for (int c = 0; c < EFD; ++c) {
        float w = W2T[c*EFD + o];
        const float4* fr = (const float4*)(&feat[c][h*16]);
        float4 a0 = fr[0], a1 = fr[1], a2 = fr[2], a3 = fr[3];
        acc2[0]  = fmaf(w, a0.x, acc2[0]);  acc2[1]  = fmaf(w, a0.y, acc2[1]);
        acc2[2]  = fmaf(w, a0.z, acc2[2]);  acc2[3]  = fmaf(w, a0.w, acc2[3]);
        acc2[4]  = fmaf(w, a1.x, acc2[4]);  acc2[5]  = fmaf(w, a1.y, acc2[5]);
        acc2[6]  = fmaf(w, a1.z, acc2[6]);  acc2[7]  = fmaf(w, a1.w, acc2[7]);
        acc2[8]  = fmaf(w, a2.x, acc2[8]);  acc2[9]  = fmaf(w, a2.y, acc2[9]);
        acc2[10] = fmaf(w, a2.z, acc2[10]); acc2[11] = fmaf(w, a2.w, acc2[11]);
        acc2[12] = fmaf(w, a3.x, acc2[12]); acc2[13] = fmaf(w, a3.y, acc2[13]);
        acc2[14] = fmaf(w, a3.z, acc2[14]); acc2[15] = fmaf(w, a3.w, acc2[15]);
    }
    float pb = proj_b[o];
    #pragma unroll
    for (int m = 0; m < 16; ++m) {
        int e = h*16 + m;
        out[(size_t)(e0 + e) * EFD + o] = acc2[m] + pb;
    }
}

// ---------------------------------------------------------------- launch
extern "C" void kernel_launch(void* const* d_in, const int* in_sizes, int n_in,
                              void* d_out, int out_size, void* d_ws, size_t ws_size,
                              hipStream_t stream) {
    const float* coords   = (const float*)d_in[0];
    const float* noise    = (const float*)d_in[1];
    const float* mask     = (const float*)d_in[2];
    const int*   res_idx  = (const int*)  d_in[3];
    const int*   chain_ix = (const int*)  d_in[4];
    const float* w_pos_w  = (const float*)d_in[5];
    const float* w_pos_b  = (const float*)d_in[6];
    const float* w_e_w    = (const float*)d_in[7];
    const float* nsc      = (const float*)d_in[8];
    const float* nbi      = (const float*)d_in[9];
    const float* w_proj   = (const float*)d_in[10];
    const float* w_proj_b = (const float*)d_in[11];

    float* out  = (float*)d_out;
    float* ws   = (float*)d_ws;
    int*   nbrI = (int*)(ws + WS_NBR);
    float* nbrF = out + (size_t)LRES * KNB * EFD;

    int prepN = LRES + FDIM*EFD + EFD*EFD;
    prep_kernel<<<(prepN + 255)/256, 256, 0, stream>>>(coords, noise, w_e_w, w_proj, ws);
    topk_kernel<<<LRES, 256, 0, stream>>>(ws, mask, nbrF, nbrI);
    edge_kernel<<<(LRES*KNB)/32, 256, 0, stream>>>(ws, nbrI, res_idx, chain_ix,
                                                   w_pos_w, w_pos_b, nsc, nbi,
                                                   w_proj_b, out);
}

// Round 7
// 680.797 us; speedup vs baseline: 2.0477x; 2.0477x over previous
//
#include <hip/hip_runtime.h>
#include <hip/hip_bf16.h>

#define LRES 8192
#define KNB 48
#define MAXREL 32
#define EFD 128
#define POS_DIM 16
#define RBF_BINS 16
#define NPAIR 25
#define FDIM (POS_DIM + NPAIR*RBF_BINS)   // 416

typedef __attribute__((ext_vector_type(8))) short bf16x8;
typedef __attribute__((ext_vector_type(4))) float f32x4;

// workspace layout (float offsets)
#define WS_BB   0                          // 8192*15 = 122880
#define WS_CA4  (WS_BB + LRES*15)          // 8192*4  = 32768  -> 155648
#define WS_W1F  (WS_CA4 + LRES*4)          // 208 frags * 512 bf16 = 53248 f32
#define WS_W2F  (WS_W1F + 53248)           // 32 frags * 512 bf16 = 8192 f32 (16384 reserved)
#define WS_NBR  (WS_W2F + 16384)           // 393216 ints

__device__ __forceinline__ unsigned f2bf(float f) {
    unsigned b = __float_as_uint(f);
    return (b + 0x7FFFu + ((b >> 16) & 1u)) >> 16;   // RNE bf16 bits
}
__device__ __forceinline__ float bf2f(unsigned u) {
    return __uint_as_float(u << 16);
}

// ---------------------------------------------------------------- prep
// bb/ca + frag-packed bf16 hi/lo weights.
// Frag f=(kt*8+ct)*2+p: lane holds 8 bf16 = W[n=ct*16+(l&15)][k=kt*32+(l>>4)*8+j]
// (B-operand layout; A uses the same (lane-group,elem)->k map, so any k-perm
// uncertainty cancels in the dot product)
__global__ __launch_bounds__(256) void prep_kernel(
    const float* __restrict__ coords, const float* __restrict__ noise,
    const float* __restrict__ w_e_w, const float* __restrict__ w_proj,
    float* __restrict__ ws)
{
    int t = blockIdx.x * blockDim.x + threadIdx.x;
    if (t < LRES) {
        float X[12];
        #pragma unroll
        for (int q = 0; q < 12; ++q) X[q] = coords[t*12+q] + 0.1f * noise[t*12+q];
        float Nx=X[0],Ny=X[1],Nz=X[2];
        float Ax=X[3],Ay=X[4],Az=X[5];
        float Cx=X[6],Cy=X[7],Cz=X[8];
        float Ox=X[9],Oy=X[10],Oz=X[11];
        float bx=Ax-Nx, by=Ay-Ny, bz=Az-Nz;
        float cx=Cx-Ax, cy=Cy-Ay, cz=Cz-Az;
        float ax = by*cz - bz*cy;
        float ay = bz*cx - bx*cz;
        float az = bx*cy - by*cx;
        float Bx = -0.58273431f*ax + 0.56802827f*bx - 0.54067466f*cx + Ax;
        float By = -0.58273431f*ay + 0.56802827f*by - 0.54067466f*cy + Ay;
        float Bz = -0.58273431f*az + 0.56802827f*bz - 0.54067466f*cz + Az;
        float* bb = ws + WS_BB + t*15;
        bb[0]=Nx; bb[1]=Ny; bb[2]=Nz;
        bb[3]=Ax; bb[4]=Ay; bb[5]=Az;
        bb[6]=Cx; bb[7]=Cy; bb[8]=Cz;
        bb[9]=Ox; bb[10]=Oy; bb[11]=Oz;
        bb[12]=Bx; bb[13]=By; bb[14]=Bz;
        float* ca = ws + WS_CA4 + t*4;
        ca[0]=Ax; ca[1]=Ay; ca[2]=Az; ca[3]=0.f;
    } else if (t < LRES + 13312) {               // W1F: 208 frags x 64 lanes
        int q = t - LRES;
        int f1 = q >> 6, lane = q & 63;
        int p = f1 & 1, ct = (f1 >> 1) & 7, kt = f1 >> 4;
        int n = ct*16 + (lane & 15);
        int kb = kt*32 + (lane >> 4)*8;
        bf16x8 vv;
        #pragma unroll
        for (int j = 0; j < 8; ++j) {
            float w = w_e_w[n*FDIM + kb + j];
            unsigned hb = f2bf(w);
            vv[j] = (short)(p ? f2bf(w - bf2f(hb)) : hb);
        }
        *(bf16x8*)((unsigned short*)(ws + WS_W1F) + f1*512 + lane*8) = vv;
    } else if (t < LRES + 13312 + 2048) {        // W2F: 32 frags x 64 lanes
        int q = t - LRES - 13312;
        int f2 = q >> 6, lane = q & 63;
        int p = f2 & 1, ct = (f2 >> 1) & 7, kt = f2 >> 4;
        int o = ct*16 + (lane & 15);
        int kb = kt*32 + (lane >> 4)*8;
        bf16x8 vv;
        #pragma unroll
        for (int j = 0; j < 8; ++j) {
            float w = w_proj[o*EFD + kb + j];
            unsigned hb = f2bf(w);
            vv[j] = (short)(p ? f2bf(w - bf2f(hb)) : hb);
        }
        *(bf16x8*)((unsigned short*)(ws + WS_W2F) + f2*512 + lane*8) = vv;
    }
}

// ---------------------------------------------------------------- top-K (validated round 2)
__global__ __launch_bounds__(256) void topk_kernel(
    const float* __restrict__ ws, const float* __restrict__ mask,
    float* __restrict__ nbr_f, int* __restrict__ nbr_i)
{
    const int row = blockIdx.x;
    const int tid = threadIdx.x;
    __shared__ int s_red[4];
    __shared__ int s_cnt;
    __shared__ unsigned long long s_list[256];

    const float4* ca4 = (const float4*)(ws + WS_CA4);
    float4 ci = ca4[row];
    bool mi = (mask[row] != 0.0f);

    unsigned int v[32];
    #pragma unroll
    for (int q = 0; q < 32; ++q) {
        int j = tid + q*256;
        float4 cj = ca4[j];
        float dx = cj.x - ci.x, dy = cj.y - ci.y, dz = cj.z - ci.z;
        float d = sqrtf(dx*dx + dy*dy + dz*dz + 1e-6f);
        bool valid = mi && (mask[j] != 0.0f);
        v[q] = valid ? __float_as_uint(d) : 0x7F800000u;
    }

    unsigned int lo = 0, hi = 0x7F800000u;
    while (lo < hi) {
        unsigned int mid = lo + ((hi - lo) >> 1);
        int c = 0;
        #pragma unroll
        for (int q = 0; q < 32; ++q) c += (v[q] <= mid) ? 1 : 0;
        #pragma unroll
        for (int s = 1; s < 64; s <<= 1) c += __shfl_xor(c, s);
        if ((tid & 63) == 0) s_red[tid >> 6] = c;
        __syncthreads();
        c = s_red[0] + s_red[1] + s_red[2] + s_red[3];
        __syncthreads();
        if (c >= KNB) hi = mid; else lo = mid + 1;
    }

    if (tid == 0) s_cnt = 0;
    __syncthreads();
    #pragma unroll
    for (int q = 0; q < 32; ++q) {
        if (v[q] <= lo) {
            int pos = atomicAdd(&s_cnt, 1);
            if (pos < 256)
                s_list[pos] = ((unsigned long long)v[q] << 32) | (unsigned int)(tid + q*256);
        }
    }
    __syncthreads();
    int cnt = s_cnt; if (cnt > 256) cnt = 256;
    if (tid >= cnt) s_list[tid] = 0xFFFFFFFFFFFFFFFFull;
    __syncthreads();

    for (int k = 2; k <= 256; k <<= 1) {
        for (int s = k >> 1; s > 0; s >>= 1) {
            int ixj = tid ^ s;
            if (ixj > tid) {
                unsigned long long a = s_list[tid], b = s_list[ixj];
                bool up = ((tid & k) == 0);
                if ((a > b) == up) { s_list[tid] = b; s_list[ixj] = a; }
            }
            __syncthreads();
        }
    }

    if (tid < KNB) {
        unsigned int j = (unsigned int)(s_list[tid] & 0xFFFFFFFFu);
        nbr_f[row*KNB + tid] = (float)j;
        nbr_i[row*KNB + tid] = (int)j;
    }
}

// ---------------------------------------------------------------- edges (MFMA)
// 4 independent waves/block; wave owns 64 edges (4 M-tiles) x 128 outputs.
// A-frags built in registers (lane l: edge l&15, k=(l>>4)*8+j); split-bf16
// 3-MFMA (hh + lh + hl) per tile. B-frags streamed one c at a time.
// ALL acc/acc2 indexing is compile-time-constant (rule #20: no scratch demotion).
__global__ __launch_bounds__(256, 2) void edge_kernel(
    const float* __restrict__ ws, const int* __restrict__ nbr_i,
    const int* __restrict__ res_idx, const int* __restrict__ chain_idx,
    const float* __restrict__ w_pos_w, const float* __restrict__ w_pos_b,
    const float* __restrict__ nsc, const float* __restrict__ nbi,
    const float* __restrict__ proj_b, float* __restrict__ out)
{
    __shared__ unsigned int nst[4][2048];   // per-wave 16x128 u32 (hi16|lo16), XOR-swizzled

    const int tid  = threadIdx.x;
    const int wv   = tid >> 6;
    const int lane = tid & 63;
    const int g    = lane >> 4;
    const int r    = lane & 15;
    const int eb   = blockIdx.x * 256 + wv * 64;

    const float*  bbp = ws + WS_BB;
    const bf16x8* w1f = (const bf16x8*)(ws + WS_W1F);
    const bf16x8* w2f = (const bf16x8*)(ws + WS_W2F);

    int it[4], jt[4], enc[4];
    #pragma unroll
    for (int t = 0; t < 4; ++t) {
        int gid = eb + t*16 + r;
        int i = gid / KNB;
        int j = nbr_i[gid];
        it[t] = i*15; jt[t] = j*15;
        int off = res_idx[i] - res_idx[j] + MAXREL;
        off = off < 0 ? 0 : (off > 2*MAXREL ? 2*MAXREL : off);
        enc[t] = (chain_idx[i] == chain_idx[j]) ? off : (2*MAXREL + 1);
    }

    f32x4 acc[4][8];
    #pragma unroll
    for (int t = 0; t < 4; ++t)
        #pragma unroll
        for (int c = 0; c < 8; ++c)
            acc[t][c] = (f32x4){0.f, 0.f, 0.f, 0.f};

    // ---------------- GEMM1: K = 416 = 13 steps of 32
    #pragma unroll 1
    for (int ks = 0; ks < 13; ++ks) {
        const int k0 = ks*32 + g*8;
        bf16x8 Ah[4], Al[4];
        #pragma unroll
        for (int t = 0; t < 4; ++t) {
            float f[8];
            if (k0 < 16) {                       // positional dims (ks==0, g<2)
                #pragma unroll
                for (int j = 0; j < 8; ++j)
                    f[j] = w_pos_w[(k0+j)*(2*MAXREL+2) + enc[t]] + w_pos_b[k0+j];
            } else {                             // RBF dims
                int kk = k0 - 16;
                int pp = kk >> 4;                // atom-pair 0..24
                int b0 = kk & 8;                 // bin half
                int a  = pp / 5, b = pp - a*5;
                const float* pi = bbp + it[t] + a*3;
                const float* pj = bbp + jt[t] + b*3;
                float dx = pi[0]-pj[0], dy = pi[1]-pj[1], dz = pi[2]-pj[2];
                float d = sqrtf(dx*dx + dy*dy + dz*dz + 1e-6f);
                #pragma unroll
                for (int j = 0; j < 8; ++j) {
                    float mu = 2.0f + (float)(b0 + j) * (4.0f/3.0f);
                    float u = (d - mu) * 0.8f;
                    f[j] = __expf(-u*u);
                }
            }
            #pragma unroll
            for (int j = 0; j < 8; ++j) {
                unsigned hb = f2bf(f[j]);
                Ah[t][j] = (short)hb;
                Al[t][j] = (short)f2bf(f[j] - bf2f(hb));
            }
        }
        #pragma unroll
        for (int c = 0; c < 8; ++c) {
            bf16x8 Bh = w1f[((ks*8 + c)*2 + 0)*64 + lane];
            bf16x8 Bl = w1f[((ks*8 + c)*2 + 1)*64 + lane];
            #pragma unroll
            for (int t = 0; t < 4; ++t) {
                acc[t][c] = __builtin_amdgcn_mfma_f32_16x16x32_bf16(Ah[t], Bh, acc[t][c], 0, 0, 0);
                acc[t][c] = __builtin_amdgcn_mfma_f32_16x16x32_bf16(Al[t], Bh, acc[t][c], 0, 0, 0);
                acc[t][c] = __builtin_amdgcn_mfma_f32_16x16x32_bf16(Ah[t], Bl, acc[t][c], 0, 0, 0);
            }
        }
    }

    float scl[8], bia[8], pb[8];
    #pragma unroll
    for (int c = 0; c < 8; ++c) {
        scl[c] = nsc[c*16 + r];
        bia[c] = nbi[c*16 + r];
        pb[c]  = proj_b[c*16 + r];
    }

    // ---------------- per M-tile: LayerNorm -> stash -> GEMM2 -> store
    // FULLY UNROLLED (acc[t] must be static-indexed; #pragma unroll 1 here
    // would demote all 128 acc VGPRs to scratch -- rule #20)
    #pragma unroll
    for (int t = 0; t < 4; ++t) {
        // C/D layout (m89): col(o-part)=r, row(edge)=g*4+m
        float mean[4], rstd[4];
        #pragma unroll
        for (int m = 0; m < 4; ++m) {
            float s = 0.f;
            #pragma unroll
            for (int c = 0; c < 8; ++c) s += acc[t][c][m];
            s += __shfl_xor(s, 1); s += __shfl_xor(s, 2);
            s += __shfl_xor(s, 4); s += __shfl_xor(s, 8);
            mean[m] = s * (1.0f/128.0f);
        }
        #pragma unroll
        for (int m = 0; m < 4; ++m) {
            float s = 0.f;
            #pragma unroll
            for (int c = 0; c < 8; ++c) {
                float dv = acc[t][c][m] - mean[m];
                s += dv*dv;
            }
            s += __shfl_xor(s, 1); s += __shfl_xor(s, 2);
            s += __shfl_xor(s, 4); s += __shfl_xor(s, 8);
            rstd[m] = rsqrtf(s * (1.0f/128.0f) + 1e-5f);
        }
        // normalize + stash (hi<<16|lo), XOR-swizzle keyed on edge (bits 2-4)
        #pragma unroll
        for (int m = 0; m < 4; ++m) {
            int e   = 4*g + m;
            int key = (e & 7) << 2;
            unsigned rowb = e*128;
            #pragma unroll
            for (int c = 0; c < 8; ++c) {
                float x = (acc[t][c][m] - mean[m]) * rstd[m] * scl[c] + bia[c];
                unsigned hb = f2bf(x);
                unsigned lb = f2bf(x - bf2f(hb));
                nst[wv][rowb + ((c*16 + r) ^ key)] = (hb << 16) | lb;
            }
        }
        // GEMM2: out2[e][o] = sum_c n[e][c] * W2[o][c]  (same-wave LDS: in-order, no barrier)
        f32x4 acc2[8];
        #pragma unroll
        for (int c = 0; c < 8; ++c) acc2[c] = (f32x4){0.f, 0.f, 0.f, 0.f};

        const int rowr = r*128;
        const int kyr  = (r & 7) << 2;
        #pragma unroll
        for (int ks2 = 0; ks2 < 4; ++ks2) {
            int c0 = ks2*32 + g*8;               // 8-aligned; ^kyr keeps bits 0-1 -> uint4 ok
            uint4 u0 = *(const uint4*)&nst[wv][rowr + ((c0    ) ^ kyr)];
            uint4 u1 = *(const uint4*)&nst[wv][rowr + ((c0 + 4) ^ kyr)];
            bf16x8 Ah, Al;
            Ah[0]=(short)(u0.x>>16); Al[0]=(short)(u0.x&0xFFFF);
            Ah[1]=(short)(u0.y>>16); Al[1]=(short)(u0.y&0xFFFF);
            Ah[2]=(short)(u0.z>>16); Al[2]=(short)(u0.z&0xFFFF);
            Ah[3]=(short)(u0.w>>16); Al[3]=(short)(u0.w&0xFFFF);
            Ah[4]=(short)(u1.x>>16); Al[4]=(short)(u1.x&0xFFFF);
            Ah[5]=(short)(u1.y>>16); Al[5]=(short)(u1.y&0xFFFF);
            Ah[6]=(short)(u1.z>>16); Al[6]=(short)(u1.z&0xFFFF);
            Ah[7]=(short)(u1.w>>16); Al[7]=(short)(u1.w&0xFFFF);
            #pragma unroll
            for (int c = 0; c < 8; ++c) {
                bf16x8 B2h = w2f[((ks2*8 + c)*2 + 0)*64 + lane];
                bf16x8 B2l = w2f[((ks2*8 + c)*2 + 1)*64 + lane];
                acc2[c] = __builtin_amdgcn_mfma_f32_16x16x32_bf16(Ah, B2h, acc2[c], 0, 0, 0);
                acc2[c] = __builtin_amdgcn_mfma_f32_16x16x32_bf16(Al, B2h, acc2[c], 0, 0, 0);
                acc2[c] = __builtin_amdgcn_mfma_f32_16x16x32_bf16(Ah, B2l, acc2[c], 0, 0, 0);
            }
        }
        #pragma unroll
        for (int m = 0; m < 4; ++m) {
            size_t ro = (size_t)(eb + t*16 + 4*g + m) * EFD + r;
            #pragma unroll
            for (int c = 0; c < 8; ++c)
                out[ro + c*16] = acc2[c][m] + pb[c];
        }
    }
}

// ---------------------------------------------------------------- launch
extern "C" void kernel_launch(void* const* d_in, const int* in_sizes, int n_in,
                              void* d_out, int out_size, void* d_ws, size_t ws_size,
                              hipStream_t stream) {
    const float* coords   = (const float*)d_in[0];
    const float* noise    = (const float*)d_in[1];
    const float* mask     = (const float*)d_in[2];
    const int*   res_idx  = (const int*)  d_in[3];
    const int*   chain_ix = (const int*)  d_in[4];
    const float* w_pos_w  = (const float*)d_in[5];
    const float* w_pos_b  = (const float*)d_in[6];
    const float* w_e_w    = (const float*)d_in[7];
    const float* nsc      = (const float*)d_in[8];
    const float* nbi      = (const float*)d_in[9];
    const float* w_proj   = (const float*)d_in[10];
    const float* w_proj_b = (const float*)d_in[11];

    float* out  = (float*)d_out;
    float* ws   = (float*)d_ws;
    int*   nbrI = (int*)(ws + WS_NBR);
    float* nbrF = out + (size_t)LRES * KNB * EFD;

    int prepN = LRES + 13312 + 2048;
    prep_kernel<<<(prepN + 255)/256, 256, 0, stream>>>(coords, noise, w_e_w, w_proj, ws);
    topk_kernel<<<LRES, 256, 0, stream>>>(ws, mask, nbrF, nbrI);
    edge_kernel<<<(LRES*KNB)/256, 256, 0, stream>>>(ws, nbrI, res_idx, chain_ix,
                                                    w_pos_w, w_pos_b, nsc, nbi,
                                                    w_proj_b, out);
}

// Round 8
// 548.092 us; speedup vs baseline: 2.5435x; 1.2421x over previous
//
#include <hip/hip_runtime.h>
#include <hip/hip_bf16.h>

#define LRES 8192
#define KNB 48
#define MAXREL 32
#define EFD 128
#define POS_DIM 16
#define RBF_BINS 16
#define NPAIR 25
#define FDIM (POS_DIM + NPAIR*RBF_BINS)   // 416

typedef __attribute__((ext_vector_type(8))) short bf16x8;
typedef __attribute__((ext_vector_type(4))) float f32x4;

// workspace layout (float offsets)
#define WS_BB   0                          // 8192*15 = 122880
#define WS_CA4  (WS_BB + LRES*15)          // 8192*4  = 32768  -> 155648
#define WS_W1F  (WS_CA4 + LRES*4)          // 208 frags * 512 bf16 = 53248 f32
#define WS_W2F  (WS_W1F + 53248)           // 64 frags * 512 bf16 = 16384 f32
#define WS_NBR  (WS_W2F + 16384)           // 393216 ints

__device__ __forceinline__ unsigned f2bf(float f) {
    unsigned b = __float_as_uint(f);
    return (b + 0x7FFFu + ((b >> 16) & 1u)) >> 16;   // RNE bf16 bits
}
__device__ __forceinline__ float bf2f(unsigned u) {
    return __uint_as_float(u << 16);
}

// ---------------------------------------------------------------- prep
// bb/ca + frag-packed bf16 hi/lo weights.
// Frag f=(kt*8+ct)*2+p: lane holds 8 bf16 = W[n=ct*16+(l&15)][k=kt*32+(l>>4)*8+j]
// W1F: 13kt*8ct*2p = 208 frags. W2F: 4kt*8ct*2p = 64 frags (ROUND-7 BUG: was 32
// -> ks2>=2 read 0xAA poison -> GEMM2 dropped channels 64..127, absmax 2.59).
__global__ __launch_bounds__(256) void prep_kernel(
    const float* __restrict__ coords, const float* __restrict__ noise,
    const float* __restrict__ w_e_w, const float* __restrict__ w_proj,
    float* __restrict__ ws)
{
    int t = blockIdx.x * blockDim.x + threadIdx.x;
    if (t < LRES) {
        float X[12];
        #pragma unroll
        for (int q = 0; q < 12; ++q) X[q] = coords[t*12+q] + 0.1f * noise[t*12+q];
        float Nx=X[0],Ny=X[1],Nz=X[2];
        float Ax=X[3],Ay=X[4],Az=X[5];
        float Cx=X[6],Cy=X[7],Cz=X[8];
        float Ox=X[9],Oy=X[10],Oz=X[11];
        float bx=Ax-Nx, by=Ay-Ny, bz=Az-Nz;
        float cx=Cx-Ax, cy=Cy-Ay, cz=Cz-Az;
        float ax = by*cz - bz*cy;
        float ay = bz*cx - bx*cz;
        float az = bx*cy - by*cx;
        float Bx = -0.58273431f*ax + 0.56802827f*bx - 0.54067466f*cx + Ax;
        float By = -0.58273431f*ay + 0.56802827f*by - 0.54067466f*cy + Ay;
        float Bz = -0.58273431f*az + 0.56802827f*bz - 0.54067466f*cz + Az;
        float* bb = ws + WS_BB + t*15;
        bb[0]=Nx; bb[1]=Ny; bb[2]=Nz;
        bb[3]=Ax; bb[4]=Ay; bb[5]=Az;
        bb[6]=Cx; bb[7]=Cy; bb[8]=Cz;
        bb[9]=Ox; bb[10]=Oy; bb[11]=Oz;
        bb[12]=Bx; bb[13]=By; bb[14]=Bz;
        float* ca = ws + WS_CA4 + t*4;
        ca[0]=Ax; ca[1]=Ay; ca[2]=Az; ca[3]=0.f;
    } else if (t < LRES + 13312) {               // W1F: 208 frags x 64 lanes
        int q = t - LRES;
        int f1 = q >> 6, lane = q & 63;
        int p = f1 & 1, ct = (f1 >> 1) & 7, kt = f1 >> 4;
        int n = ct*16 + (lane & 15);
        int kb = kt*32 + (lane >> 4)*8;
        bf16x8 vv;
        #pragma unroll
        for (int j = 0; j < 8; ++j) {
            float w = w_e_w[n*FDIM + kb + j];
            unsigned hb = f2bf(w);
            vv[j] = (short)(p ? f2bf(w - bf2f(hb)) : hb);
        }
        *(bf16x8*)((unsigned short*)(ws + WS_W1F) + f1*512 + lane*8) = vv;
    } else if (t < LRES + 13312 + 4096) {        // W2F: 64 frags x 64 lanes
        int q = t - LRES - 13312;
        int f2 = q >> 6, lane = q & 63;
        int p = f2 & 1, ct = (f2 >> 1) & 7, kt = f2 >> 4;   // kt in [0,4)
        int o = ct*16 + (lane & 15);
        int kb = kt*32 + (lane >> 4)*8;
        bf16x8 vv;
        #pragma unroll
        for (int j = 0; j < 8; ++j) {
            float w = w_proj[o*EFD + kb + j];
            unsigned hb = f2bf(w);
            vv[j] = (short)(p ? f2bf(w - bf2f(hb)) : hb);
        }
        *(bf16x8*)((unsigned short*)(ws + WS_W2F) + f2*512 + lane*8) = vv;
    }
}

// ---------------------------------------------------------------- top-K
// Coarse binary search on (v>>16) -- 15 iters, 1 barrier each (double-buffered
// s_red). T = (v48>>16) exactly, so collecting v <= (T<<16)|0xFFFF keeps all
// top-48 plus ~1 extra in the same 2^-7-rel bin. Typical cnt<=64 -> barrier-free
// wave64 shfl-bitonic; cnt>64 -> 256-bitonic fallback (round-2-validated).
__global__ __launch_bounds__(256) void topk_kernel(
    const float* __restrict__ ws, const float* __restrict__ mask,
    float* __restrict__ nbr_f, int* __restrict__ nbr_i)
{
    const int row = blockIdx.x;
    const int tid = threadIdx.x;
    __shared__ int s_red[2][4];
    __shared__ int s_cnt;
    __shared__ unsigned long long s_list[256];

    const float4* ca4 = (const float4*)(ws + WS_CA4);
    float4 ci = ca4[row];
    bool mi = (mask[row] != 0.0f);

    unsigned int v[32];
    #pragma unroll
    for (int q = 0; q < 32; ++q) {
        int j = tid + q*256;
        float4 cj = ca4[j];
        float dx = cj.x - ci.x, dy = cj.y - ci.y, dz = cj.z - ci.z;
        float d = sqrtf(dx*dx + dy*dy + dz*dz + 1e-6f);
        bool valid = mi && (mask[j] != 0.0f);
        v[q] = valid ? __float_as_uint(d) : 0x7F800000u;
    }

    unsigned lo = 0, hi = 0x7F80u;     // search T = v>>16
    int par = 0;
    while (lo < hi) {
        unsigned mid = (lo + hi) >> 1;
        unsigned M = (mid << 16) | 0xFFFFu;
        int c = 0;
        #pragma unroll
        for (int q = 0; q < 32; ++q) c += (v[q] <= M) ? 1 : 0;
        #pragma unroll
        for (int s = 1; s < 64; s <<= 1) c += __shfl_xor(c, s);
        if ((tid & 63) == 0) s_red[par][tid >> 6] = c;
        __syncthreads();
        c = s_red[par][0] + s_red[par][1] + s_red[par][2] + s_red[par][3];
        par ^= 1;
        if (c >= KNB) hi = mid; else lo = mid + 1;
    }
    const unsigned M = (lo << 16) | 0xFFFFu;

    if (tid == 0) s_cnt = 0;
    __syncthreads();
    #pragma unroll
    for (int q = 0; q < 32; ++q) {
        if (v[q] <= M) {
            int pos = atomicAdd(&s_cnt, 1);
            if (pos < 256)
                s_list[pos] = ((unsigned long long)v[q] << 32) | (unsigned int)(tid + q*256);
        }
    }
    __syncthreads();
    int cnt = s_cnt; if (cnt > 256) cnt = 256;
    if (tid >= cnt) s_list[tid] = 0xFFFFFFFFFFFFFFFFull;
    __syncthreads();

    if (cnt <= 64) {
        // wave-0 in-register bitonic sort of 64, zero barriers
        if (tid < 64) {
            unsigned long long x = s_list[tid];
            #pragma unroll
            for (int k = 2; k <= 64; k <<= 1) {
                #pragma unroll
                for (int s = k >> 1; s > 0; s >>= 1) {
                    unsigned long long y = __shfl_xor(x, s);
                    bool up    = ((tid & k) == 0);
                    bool lower = ((tid & s) == 0);
                    bool wmin  = (lower == up);
                    unsigned long long mn = x < y ? x : y;
                    unsigned long long mx = x < y ? y : x;
                    x = wmin ? mn : mx;
                }
            }
            if (tid < KNB) {
                unsigned int j = (unsigned int)(x & 0xFFFFFFFFu);
                nbr_f[row*KNB + tid] = (float)j;
                nbr_i[row*KNB + tid] = (int)j;
            }
        }
    } else {
        for (int k = 2; k <= 256; k <<= 1) {
            for (int s = k >> 1; s > 0; s >>= 1) {
                int ixj = tid ^ s;
                if (ixj > tid) {
                    unsigned long long a = s_list[tid], b = s_list[ixj];
                    bool up = ((tid & k) == 0);
                    if ((a > b) == up) { s_list[tid] = b; s_list[ixj] = a; }
                }
                __syncthreads();
            }
        }
        if (tid < KNB) {
            unsigned int j = (unsigned int)(s_list[tid] & 0xFFFFFFFFu);
            nbr_f[row*KNB + tid] = (float)j;
            nbr_i[row*KNB + tid] = (int)j;
        }
    }
}

// ---------------------------------------------------------------- edges (MFMA)
// 4 independent waves/block; wave owns 64 edges (4 M-tiles) x 128 outputs.
// A-side is plain bf16 (hi only); weights keep hi+lo split -> 2 MFMAs per
// (c,t) pair: Ah*Bh + Ah*Bl. ks-loop unroll 2 for load/MFMA overlap.
__global__ __launch_bounds__(256, 2) void edge_kernel(
    const float* __restrict__ ws, const int* __restrict__ nbr_i,
    const int* __restrict__ res_idx, const int* __restrict__ chain_idx,
    const float* __restrict__ w_pos_w, const float* __restrict__ w_pos_b,
    const float* __restrict__ nsc, const float* __restrict__ nbi,
    const float* __restrict__ proj_b, float* __restrict__ out)
{
    __shared__ unsigned int nst[4][2048];   // per-wave 16x128 u32 (bf16 hi<<16), XOR-swizzled

    const int tid  = threadIdx.x;
    const int wv   = tid >> 6;
    const int lane = tid & 63;
    const int g    = lane >> 4;
    const int r    = lane & 15;
    const int eb   = blockIdx.x * 256 + wv * 64;

    const float*  bbp = ws + WS_BB;
    const bf16x8* w1f = (const bf16x8*)(ws + WS_W1F);
    const bf16x8* w2f = (const bf16x8*)(ws + WS_W2F);

    int it[4], jt[4], enc[4];
    #pragma unroll
    for (int t = 0; t < 4; ++t) {
        int gid = eb + t*16 + r;
        int i = gid / KNB;
        int j = nbr_i[gid];
        it[t] = i*15; jt[t] = j*15;
        int off = res_idx[i] - res_idx[j] + MAXREL;
        off = off < 0 ? 0 : (off > 2*MAXREL ? 2*MAXREL : off);
        enc[t] = (chain_idx[i] == chain_idx[j]) ? off : (2*MAXREL + 1);
    }

    f32x4 acc[4][8];
    #pragma unroll
    for (int t = 0; t < 4; ++t)
        #pragma unroll
        for (int c = 0; c < 8; ++c)
            acc[t][c] = (f32x4){0.f, 0.f, 0.f, 0.f};

    // ---------------- GEMM1: K = 416 = 13 steps of 32
    #pragma unroll 2
    for (int ks = 0; ks < 13; ++ks) {
        const int k0 = ks*32 + g*8;
        bf16x8 Ah[4];
        #pragma unroll
        for (int t = 0; t < 4; ++t) {
            float f[8];
            if (k0 < 16) {                       // positional dims (ks==0, g<2)
                #pragma unroll
                for (int j = 0; j < 8; ++j)
                    f[j] = w_pos_w[(k0+j)*(2*MAXREL+2) + enc[t]] + w_pos_b[k0+j];
            } else {                             // RBF dims
                int kk = k0 - 16;
                int pp = kk >> 4;                // atom-pair 0..24
                int b0 = kk & 8;                 // bin half
                int a  = pp / 5, b = pp - a*5;
                const float* pi = bbp + it[t] + a*3;
                const float* pj = bbp + jt[t] + b*3;
                float dx = pi[0]-pj[0], dy = pi[1]-pj[1], dz = pi[2]-pj[2];
                float d = sqrtf(dx*dx + dy*dy + dz*dz + 1e-6f);
                #pragma unroll
                for (int j = 0; j < 8; ++j) {
                    float mu = 2.0f + (float)(b0 + j) * (4.0f/3.0f);
                    float u = (d - mu) * 0.8f;
                    f[j] = __expf(-u*u);
                }
            }
            #pragma unroll
            for (int j = 0; j < 8; ++j) Ah[t][j] = (short)f2bf(f[j]);
        }
        #pragma unroll
        for (int c = 0; c < 8; ++c) {
            bf16x8 Bh = w1f[((ks*8 + c)*2 + 0)*64 + lane];
            bf16x8 Bl = w1f[((ks*8 + c)*2 + 1)*64 + lane];
            #pragma unroll
            for (int t = 0; t < 4; ++t) {
                acc[t][c] = __builtin_amdgcn_mfma_f32_16x16x32_bf16(Ah[t], Bh, acc[t][c], 0, 0, 0);
                acc[t][c] = __builtin_amdgcn_mfma_f32_16x16x32_bf16(Ah[t], Bl, acc[t][c], 0, 0, 0);
            }
        }
    }

    float scl[8], bia[8], pb[8];
    #pragma unroll
    for (int c = 0; c < 8; ++c) {
        scl[c] = nsc[c*16 + r];
        bia[c] = nbi[c*16 + r];
        pb[c]  = proj_b[c*16 + r];
    }

    // ---------------- per M-tile: LayerNorm -> stash -> GEMM2 -> store
    // FULLY UNROLLED (static acc indexing -- rule #20)
    #pragma unroll
    for (int t = 0; t < 4; ++t) {
        // C/D layout (m89): col(o-part)=r, row(edge)=g*4+m
        float mean[4], rstd[4];
        #pragma unroll
        for (int m = 0; m < 4; ++m) {
            float s = 0.f;
            #pragma unroll
            for (int c = 0; c < 8; ++c) s += acc[t][c][m];
            s += __shfl_xor(s, 1); s += __shfl_xor(s, 2);
            s += __shfl_xor(s, 4); s += __shfl_xor(s, 8);
            mean[m] = s * (1.0f/128.0f);
        }
        #pragma unroll
        for (int m = 0; m < 4; ++m) {
            float s = 0.f;
            #pragma unroll
            for (int c = 0; c < 8; ++c) {
                float dv = acc[t][c][m] - mean[m];
                s += dv*dv;
            }
            s += __shfl_xor(s, 1); s += __shfl_xor(s, 2);
            s += __shfl_xor(s, 4); s += __shfl_xor(s, 8);
            rstd[m] = rsqrtf(s * (1.0f/128.0f) + 1e-5f);
        }
        // normalize + stash bf16 hi<<16, XOR-swizzle keyed on edge (bits 2-4)
        #pragma unroll
        for (int m = 0; m < 4; ++m) {
            int e   = 4*g + m;
            int key = (e & 7) << 2;
            unsigned rowb = e*128;
            #pragma unroll
            for (int c = 0; c < 8; ++c) {
                float x = (acc[t][c][m] - mean[m]) * rstd[m] * scl[c] + bia[c];
                nst[wv][rowb + ((c*16 + r) ^ key)] = f2bf(x) << 16;
            }
        }
        // GEMM2: out2[e][o] = sum_c n[e][c] * W2[o][c]  (same-wave LDS: in-order)
        f32x4 acc2[8];
        #pragma unroll
        for (int c = 0; c < 8; ++c) acc2[c] = (f32x4){0.f, 0.f, 0.f, 0.f};

        const int rowr = r*128;
        const int kyr  = (r & 7) << 2;
        #pragma unroll
        for (int ks2 = 0; ks2 < 4; ++ks2) {
            int c0 = ks2*32 + g*8;               // 8-aligned; ^kyr keeps bits 0-1 -> uint4 ok
            uint4 u0 = *(const uint4*)&nst[wv][rowr + ((c0    ) ^ kyr)];
            uint4 u1 = *(const uint4*)&nst[wv][rowr + ((c0 + 4) ^ kyr)];
            bf16x8 Ah;
            Ah[0]=(short)(u0.x>>16); Ah[1]=(short)(u0.y>>16);
            Ah[2]=(short)(u0.z>>16); Ah[3]=(short)(u0.w>>16);
            Ah[4]=(short)(u1.x>>16); Ah[5]=(short)(u1.y>>16);
            Ah[6]=(short)(u1.z>>16); Ah[7]=(short)(u1.w>>16);
            #pragma unroll
            for (int c = 0; c < 8; ++c) {
                bf16x8 B2h = w2f[((ks2*8 + c)*2 + 0)*64 + lane];
                bf16x8 B2l = w2f[((ks2*8 + c)*2 + 1)*64 + lane];
                acc2[c] = __builtin_amdgcn_mfma_f32_16x16x32_bf16(Ah, B2h, acc2[c], 0, 0, 0);
                acc2[c] = __builtin_amdgcn_mfma_f32_16x16x32_bf16(Ah, B2l, acc2[c], 0, 0, 0);
            }
        }
        #pragma unroll
        for (int m = 0; m < 4; ++m) {
            size_t ro = (size_t)(eb + t*16 + 4*g + m) * EFD + r;
            #pragma unroll
            for (int c = 0; c < 8; ++c)
                out[ro + c*16] = acc2[c][m] + pb[c];
        }
    }
}

// ---------------------------------------------------------------- launch
extern "C" void kernel_launch(void* const* d_in, const int* in_sizes, int n_in,
                              void* d_out, int out_size, void* d_ws, size_t ws_size,
                              hipStream_t stream) {
    const float* coords   = (const float*)d_in[0];
    const float* noise    = (const float*)d_in[1];
    const float* mask     = (const float*)d_in[2];
    const int*   res_idx  = (const int*)  d_in[3];
    const int*   chain_ix = (const int*)  d_in[4];
    const float* w_pos_w  = (const float*)d_in[5];
    const float* w_pos_b  = (const float*)d_in[6];
    const float* w_e_w    = (const float*)d_in[7];
    const float* nsc      = (const float*)d_in[8];
    const float* nbi      = (const float*)d_in[9];
    const float* w_proj   = (const float*)d_in[10];
    const float* w_proj_b = (const float*)d_in[11];

    float* out  = (float*)d_out;
    float* ws   = (float*)d_ws;
    int*   nbrI = (int*)(ws + WS_NBR);
    float* nbrF = out + (size_t)LRES * KNB * EFD;

    int prepN = LRES + 13312 + 4096;
    prep_kernel<<<(prepN + 255)/256, 256, 0, stream>>>(coords, noise, w_e_w, w_proj, ws);
    topk_kernel<<<LRES, 256, 0, stream>>>(ws, mask, nbrF, nbrI);
    edge_kernel<<<(LRES*KNB)/256, 256, 0, stream>>>(ws, nbrI, res_idx, chain_ix,
                                                    w_pos_w, w_pos_b, nsc, nbi,
                                                    w_proj_b, out);
}